// Round 7
// baseline (313.567 us; speedup 1.0000x reference)
//
#include <hip/hip_runtime.h>
#include <hip/hip_bf16.h>
#include <stdint.h>

// ---------------------------------------------------------------------------
// Single-head self-attention, B=4, S=2048, D=1024, fp32 in/out.
// Round 6b (compile fix): qkv = round-3 exact config (71.5us). score/pv use
// 64x128 tiles / 128 threads (2 waves): grid 2048/1024 blocks for 2-4x
// resident blocks/CU (round-5: both stuck at ~84us = half qkv's rate with
// only 2-4 blocks/CU from grid size). Supertile 4x4 launch order.
// Pipeline:
//   1. k_prep:  xb=bf16(x); wt=bf16(W^T) q,k,v; rowsum=0
//   2. k_qkv:   q,k,v = x@W+b (bf16)        [3][8192,1024]
//   3. k_tr:    vT = transpose(v) per batch [4][1024,2048]
//   4. k_score: P' = exp2(q@k^T*s*log2e) (bf16) + rowsum atomics
//   5. k_pv:    out = (P' @ vT^T)/rowsum (fp32 -> d_out)
// ---------------------------------------------------------------------------

typedef __attribute__((ext_vector_type(8))) short short8;   // 8 bf16 = 4 VGPR
typedef __attribute__((ext_vector_type(4))) float f32x4;    // MFMA C/D

__device__ __forceinline__ unsigned short f2bf(float f) {
  union { float f; uint32_t u; } c; c.f = f;
  uint32_t u = c.u;
  u += 0x7FFFu + ((u >> 16) & 1u);   // RNE
  return (unsigned short)(u >> 16);
}

// async global->LDS, 16B/lane; LDS dest is wave-uniform base + lane*16.
__device__ __forceinline__ void gl16(const void* g, void* l) {
  __builtin_amdgcn_global_load_lds(
      (const __attribute__((address_space(1))) unsigned int*)g,
      (__attribute__((address_space(3))) unsigned int*)l, 16, 0, 0);
}

// ------------------- qkv: 128x128 tile, 256 threads (round-3 exact) --------
// C = A @ B^T + bias[col], bf16 out. K=1024, BK=32 double-buffered.
__global__ __launch_bounds__(256) void k_qkv(
    const short* __restrict__ A, const short* __restrict__ B,
    short* __restrict__ Cb,
    const float* __restrict__ b0, const float* __restrict__ b1,
    const float* __restrict__ b2)
{
  __shared__ short lds[18432];   // 2 bufs x (sA 4096 | sB 4096); overlay 4x4608

  const int tid  = threadIdx.x;
  const int lane = tid & 63;
  const int wid  = tid >> 6;
  const int z    = blockIdx.z;
  const long tileM = (long)blockIdx.y * 128;
  const long tileN = (long)blockIdx.x * 128;
  const short* Az = A;                          // xb shared across z
  const short* Bz = B + (long)z * 1048576L;

  const int c0 = tid, c1 = 256 + tid;
  const short* gA0 = Az + (tileM + (c0 >> 2)) * 1024 + (c0 & 3) * 8;
  const short* gA1 = Az + (tileM + (c1 >> 2)) * 1024 + (c1 & 3) * 8;
  const short* gB0 = Bz + (tileN + (c0 >> 2)) * 1024 + (c0 & 3) * 8;
  const short* gB1 = Bz + (tileN + (c1 >> 2)) * 1024 + (c1 & 3) * 8;

  const int fr = lane & 15, quad = lane >> 4;
  const int waveM = (wid >> 1) * 64, waveN = (wid & 1) * 64;

  f32x4 acc[4][4] = {};

  {
    short* base = lds;
    gl16(gA0, base + c0 * 8);
    gl16(gA1, base + c1 * 8);
    gl16(gB0, base + 4096 + c0 * 8);
    gl16(gB1, base + 4096 + c1 * 8);
  }

  for (int t = 0; t < 32; ++t) {
    __syncthreads();
    if (t + 1 < 32) {
      const int kt = (t + 1) << 5;
      short* base = lds + ((t + 1) & 1) * 8192;
      gl16(gA0 + kt, base + c0 * 8);
      gl16(gA1 + kt, base + c1 * 8);
      gl16(gB0 + kt, base + 4096 + c0 * 8);
      gl16(gB1 + kt, base + 4096 + c1 * 8);
    }
    const short* sA = lds + (t & 1) * 8192;
    const short* sB = sA + 4096;
    short8 af[4], bf[4];
#pragma unroll
    for (int i = 0; i < 4; ++i)
      af[i] = *(const short8*)&sA[(waveM + i * 16 + fr) * 32 + quad * 8];
#pragma unroll
    for (int j = 0; j < 4; ++j)
      bf[j] = *(const short8*)&sB[(waveN + j * 16 + fr) * 32 + quad * 8];
#pragma unroll
    for (int i = 0; i < 4; ++i)
#pragma unroll
      for (int j = 0; j < 4; ++j)
        acc[i][j] = __builtin_amdgcn_mfma_f32_16x16x32_bf16(af[i], bf[j],
                                                            acc[i][j], 0, 0, 0);
  }

  // bf16 out via per-wave LDS transpose -> contiguous dwordx4 stores.
  // C/D layout: row=(lane>>4)*4+r, col=lane&15 (m89/m91-verified).
  __syncthreads();
  short* scr = lds + wid * 4608;   // [64][72]
  short* C = Cb + (long)z * 8388608L;
  const float* bias = (z == 0) ? b0 : ((z == 1) ? b1 : b2);
#pragma unroll
  for (int j = 0; j < 4; ++j) {
    const float bv = bias[tileN + waveN + j * 16 + fr];
#pragma unroll
    for (int i = 0; i < 4; ++i)
#pragma unroll
      for (int r = 0; r < 4; ++r)
        scr[(i * 16 + quad * 4 + r) * 72 + j * 16 + fr] =
            (short)f2bf(acc[i][j][r] + bv);
  }
  // per-wave scratch: ds_write->ds_read ordering via lgkmcnt (no barrier)
#pragma unroll
  for (int c = 0; c < 8; ++c) {
    const int row = c * 8 + (lane >> 3);
    const int col = (lane & 7) * 8;
    short8 v = *(const short8*)&scr[row * 72 + col];
    *(short8*)(C + (tileM + waveM + row) * 1024 + tileN + waveN + col) = v;
  }
}

// ------------- score/pv: 64x128 tile, 128 threads (2 waves in N) -----------
// MODE 1 (score): K=1024; C bf16 = exp2(acc*scale); rowsum atomics.
// MODE 2 (pv):    K=2048; C fp32 = acc / rowsum[row].
template <int MODE>
__device__ __forceinline__ void body128(
    int z, int tm, int tn,
    const short* __restrict__ A, const short* __restrict__ B,
    void* __restrict__ Cv, float scale, float* __restrict__ rowsum)
{
  constexpr int  LDA = (MODE == 2) ? 2048 : 1024;
  constexpr int  LDB = (MODE == 2) ? 2048 : 1024;
  constexpr int  LDC = (MODE == 1) ? 2048 : 1024;
  constexpr long SAZ = (MODE == 1) ? 2097152L : 4194304L;
  constexpr long SBZ = 2097152L;
  constexpr long SCZ = (MODE == 1) ? 4194304L : 2097152L;
  constexpr int  T   = (MODE == 2) ? 64 : 32;   // k-tiles of 32

  // 2 bufs x (sA 64x32 = 2048 | sB 128x32 = 4096) shorts = 12288 shorts.
  // epilogue overlay: per-wave [64][72] shorts at wid*4608 (<= 9216).
  __shared__ short lds[12288];

  const int tid  = threadIdx.x;
  const int lane = tid & 63;
  const int wid  = tid >> 6;          // 0..1 (N-split)
  const long tileM = (long)tm * 64;
  const long tileN = (long)tn * 128;
  const short* Az = A + (long)z * SAZ;
  const short* Bz = B + (long)z * SBZ;

  // A: 256 chunks (c=g*128+tid, g=0..1), B: 512 chunks (g=0..3).
  // chunk c -> row c>>2, col8 (c&3)*8; lds offset c*8 shorts.
  const int cA0 = tid, cA1 = 128 + tid;
  const short* gA0 = Az + (tileM + (cA0 >> 2)) * LDA + (cA0 & 3) * 8;
  const short* gA1 = Az + (tileM + (cA1 >> 2)) * LDA + (cA1 & 3) * 8;
  const int cB0 = tid, cB1 = 128 + tid, cB2 = 256 + tid, cB3 = 384 + tid;
  const short* gB0 = Bz + (tileN + (cB0 >> 2)) * LDB + (cB0 & 3) * 8;
  const short* gB1 = Bz + (tileN + (cB1 >> 2)) * LDB + (cB1 & 3) * 8;
  const short* gB2 = Bz + (tileN + (cB2 >> 2)) * LDB + (cB2 & 3) * 8;
  const short* gB3 = Bz + (tileN + (cB3 >> 2)) * LDB + (cB3 & 3) * 8;

  const int fr = lane & 15, quad = lane >> 4;
  const int waveN = wid * 64;

  f32x4 acc[4][4] = {};

  {
    short* base = lds;
    gl16(gA0, base + cA0 * 8);
    gl16(gA1, base + cA1 * 8);
    gl16(gB0, base + 2048 + cB0 * 8);
    gl16(gB1, base + 2048 + cB1 * 8);
    gl16(gB2, base + 2048 + cB2 * 8);
    gl16(gB3, base + 2048 + cB3 * 8);
  }

  for (int t = 0; t < T; ++t) {
    __syncthreads();
    if (t + 1 < T) {
      const int kt = (t + 1) << 5;
      short* base = lds + ((t + 1) & 1) * 6144;
      gl16(gA0 + kt, base + cA0 * 8);
      gl16(gA1 + kt, base + cA1 * 8);
      gl16(gB0 + kt, base + 2048 + cB0 * 8);
      gl16(gB1 + kt, base + 2048 + cB1 * 8);
      gl16(gB2 + kt, base + 2048 + cB2 * 8);
      gl16(gB3 + kt, base + 2048 + cB3 * 8);
    }
    const short* sA = lds + (t & 1) * 6144;
    const short* sB = sA + 2048;
    short8 af[4], bf[4];
#pragma unroll
    for (int i = 0; i < 4; ++i)
      af[i] = *(const short8*)&sA[(i * 16 + fr) * 32 + quad * 8];
#pragma unroll
    for (int j = 0; j < 4; ++j)
      bf[j] = *(const short8*)&sB[(waveN + j * 16 + fr) * 32 + quad * 8];
#pragma unroll
    for (int i = 0; i < 4; ++i)
#pragma unroll
      for (int j = 0; j < 4; ++j)
        acc[i][j] = __builtin_amdgcn_mfma_f32_16x16x32_bf16(af[i], bf[j],
                                                            acc[i][j], 0, 0, 0);
  }

  // C/D layout: row=(lane>>4)*4+r, col=lane&15.
  if (MODE == 1) {
#pragma unroll
    for (int i = 0; i < 4; ++i)
#pragma unroll
      for (int j = 0; j < 4; ++j)
#pragma unroll
        for (int r = 0; r < 4; ++r)
          acc[i][j][r] = exp2f(acc[i][j][r] * scale);
#pragma unroll
    for (int i = 0; i < 4; ++i)
#pragma unroll
      for (int r = 0; r < 4; ++r) {
        float s = acc[i][0][r] + acc[i][1][r] + acc[i][2][r] + acc[i][3][r];
        s += __shfl_xor(s, 1);
        s += __shfl_xor(s, 2);
        s += __shfl_xor(s, 4);
        s += __shfl_xor(s, 8);
        if (fr == 0)
          atomicAdd(&rowsum[(long)z * 2048 + tileM + i * 16 + quad * 4 + r], s);
      }
    // bf16 out via per-wave LDS transpose
    __syncthreads();                 // all staging reads done; reuse LDS
    short* scr = lds + wid * 4608;   // [64][72]
    short* C = (short*)Cv + (long)z * SCZ;
#pragma unroll
    for (int j = 0; j < 4; ++j)
#pragma unroll
      for (int i = 0; i < 4; ++i)
#pragma unroll
        for (int r = 0; r < 4; ++r)
          scr[(i * 16 + quad * 4 + r) * 72 + j * 16 + fr] =
              (short)f2bf(acc[i][j][r]);
#pragma unroll
    for (int c = 0; c < 8; ++c) {
      const int row = c * 8 + (lane >> 3);
      const int col = (lane & 7) * 8;
      short8 v = *(const short8*)&scr[row * 72 + col];
      *(short8*)(C + (tileM + row) * LDC + tileN + waveN + col) = v;
    }
  } else {
    float* C = (float*)Cv + (long)z * SCZ;
#pragma unroll
    for (int i = 0; i < 4; ++i)
#pragma unroll
      for (int r = 0; r < 4; ++r) {
        const long gr = tileM + i * 16 + quad * 4 + r;
        const float rinv = 1.0f / rowsum[(long)z * 2048 + gr];
#pragma unroll
        for (int j = 0; j < 4; ++j)
          C[gr * LDC + tileN + waveN + j * 16 + fr] = acc[i][j][r] * rinv;
      }
  }
}

// score: per z 512 blocks; supertile 4x4: super=(sm 8 x sn 4), inner 4x4.
__global__ __launch_bounds__(128) void k_score(
    const short* __restrict__ A, const short* __restrict__ B,
    void* __restrict__ Cv, float scale, float* __restrict__ rowsum)
{
  const int b = blockIdx.x;
  const int z = b >> 9, rest = b & 511;
  const int super = rest >> 4, inner = rest & 15;
  const int tm = (super >> 2) * 4 + (inner >> 2);   // 0..31
  const int tn = (super & 3) * 4 + (inner & 3);     // 0..15
  body128<1>(z, tm, tn, A, B, Cv, scale, rowsum);
}

// pv: per z 256 blocks; super=(sm 8 x sn 2), inner 4x4.
__global__ __launch_bounds__(128) void k_pv(
    const short* __restrict__ A, const short* __restrict__ B,
    void* __restrict__ Cv, float* __restrict__ rowsum)
{
  const int b = blockIdx.x;
  const int z = b >> 8, rest = b & 255;
  const int super = rest >> 4, inner = rest & 15;
  const int tm = (super >> 1) * 4 + (inner >> 2);   // 0..31
  const int tn = (super & 1) * 4 + (inner & 3);     // 0..7
  body128<2>(z, tm, tn, A, B, Cv, 1.0f, rowsum);
}

// v [4][2048][1024] bf16 -> vT [4][1024][2048] bf16
__global__ __launch_bounds__(256) void k_tr(
    const short* __restrict__ src, short* __restrict__ dst)
{
  __shared__ short tile[32][33];
  const int z = blockIdx.z;
  const int d0 = blockIdx.x * 32, t0 = blockIdx.y * 32;
  const int tx = threadIdx.x & 31, ty = threadIdx.x >> 5;
  const short* s = src + (long)z * 2048 * 1024;
  short* d = dst + (long)z * 1024 * 2048;
#pragma unroll
  for (int p = 0; p < 4; ++p)
    tile[ty + p * 8][tx] = s[(long)(t0 + ty + p * 8) * 1024 + d0 + tx];
  __syncthreads();
#pragma unroll
  for (int p = 0; p < 4; ++p)
    d[(long)(d0 + ty + p * 8) * 2048 + t0 + tx] = tile[tx][ty + p * 8];
}

// prep: blocks [0,8192) cvt x -> bf16; [8192,11264) W^T -> bf16; 11264 zero rs
__global__ __launch_bounds__(256) void k_prep(
    const float4* __restrict__ x, ushort4* __restrict__ xb,
    const float* __restrict__ Wq, const float* __restrict__ Wk,
    const float* __restrict__ Wv, short* __restrict__ WT,
    float* __restrict__ rs)
{
  __shared__ short tile[32][33];
  const int b = blockIdx.x;
  if (b < 8192) {
    const long i = (long)b * 256 + threadIdx.x;
    float4 v = x[i];
    ushort4 o;
    o.x = f2bf(v.x); o.y = f2bf(v.y); o.z = f2bf(v.z); o.w = f2bf(v.w);
    xb[i] = o;
  } else if (b < 11264) {
    const int idx = b - 8192;
    const int z = idx >> 10, rem = idx & 1023;
    const float* W = (z == 0) ? Wq : ((z == 1) ? Wk : Wv);
    short* d = WT + (long)z * 1024 * 1024;
    const int n0 = (rem & 31) * 32, d0 = (rem >> 5) * 32;
    const int tx = threadIdx.x & 31, ty = threadIdx.x >> 5;
#pragma unroll
    for (int p = 0; p < 4; ++p)
      tile[ty + p * 8][tx] = (short)f2bf(W[(long)(d0 + ty + p * 8) * 1024 + n0 + tx]);
    __syncthreads();
#pragma unroll
    for (int p = 0; p < 4; ++p)
      d[(long)(n0 + ty + p * 8) * 1024 + d0 + tx] = tile[tx][ty + p * 8];
  } else {
#pragma unroll
    for (int p = 0; p < 32; ++p)
      rs[p * 256 + threadIdx.x] = 0.0f;
  }
}

extern "C" void kernel_launch(void* const* d_in, const int* in_sizes, int n_in,
                              void* d_out, int out_size, void* d_ws, size_t ws_size,
                              hipStream_t stream) {
  const float* x  = (const float*)d_in[0];
  const float* Wq = (const float*)d_in[1];
  const float* bq = (const float*)d_in[2];
  const float* Wk = (const float*)d_in[3];
  const float* bk = (const float*)d_in[4];
  const float* Wv = (const float*)d_in[5];
  const float* bv = (const float*)d_in[6];

  char* ws = (char*)d_ws;
  short* xb  = (short*)(ws);                  // 16 MB
  short* wt  = (short*)(ws + 16777216);       // 6 MB
  short* qkv = (short*)(ws + 23068672);       // 48 MB: q | k | v
  short* Pp  = (short*)(ws + 73400320);       // 32 MB: [4][2048][2048] bf16
  float* rs  = (float*)(ws + 106954752);      // 32 KB: [4][2048] fp32
  short* vT  = (short*)(ws + 106987520);      // 16 MB: [4][1024][2048] bf16

  // 1. prep: xb, wt, rowsum=0
  k_prep<<<11265, 256, 0, stream>>>((const float4*)x, (ushort4*)xb,
                                    Wq, Wk, Wv, wt, rs);
  // 2. q,k,v = x@W+b (bf16)
  k_qkv<<<dim3(8, 64, 3), 256, 0, stream>>>(xb, wt, qkv, bq, bk, bv);
  // 3. vT per batch
  k_tr<<<dim3(32, 64, 4), 256, 0, stream>>>(qkv + 2L * 8388608, vT);
  // 4. P' = exp2(q@k^T * scale*log2e), bf16 + rowsum atomics
  k_score<<<2048, 128, 0, stream>>>(qkv, qkv + 8388608, Pp,
                                    0.03125f * 1.44269504088896f, rs);
  // 5. out = (P' @ vT^T) / rowsum  (fp32 -> d_out)
  k_pv<<<1024, 128, 0, stream>>>(Pp, vT, d_out, rs);
}

// Round 9
// 256.243 us; speedup vs baseline: 1.2237x; 1.2237x over previous
//
#include <hip/hip_runtime.h>
#include <hip/hip_bf16.h>
#include <stdint.h>

// ---------------------------------------------------------------------------
// Single-head self-attention, B=4, S=2048, D=1024, fp32 in/out.
// Round 8b (cast fix): best-known qkv (round-4: fused vT epilogue + XCD map,
// 80us, FETCH 49MB) + best-known pv (round-4 swizzled 128x128, ~85us) + NEW
// 256x256-tile score (1024 threads, 16 waves of 64x64, 64KB dbuf LDS,
// 1 gl16 chunk/thread) to halve score's L3 slab traffic (512->256MB).
// Pipeline (4 dispatches):
//   1. k_prep:  xb=bf16(x); wt=bf16(W^T); rowsum=0
//   2. k_qkv:   q,k = x@W+b (bf16); v -> vT transposed  [XCD-swizzled]
//   3. k_score: P' = exp2(q@k^T*s*log2e) (bf16) + rowsum atomics [256^2 tile]
//   4. k_pv:    out = (P' @ vT^T)/rowsum (fp32 -> d_out)
// ---------------------------------------------------------------------------

typedef __attribute__((ext_vector_type(8))) short short8;   // 8 bf16 = 4 VGPR
typedef __attribute__((ext_vector_type(4))) float f32x4;    // MFMA C/D

__device__ __forceinline__ unsigned short f2bf(float f) {
  union { float f; uint32_t u; } c; c.f = f;
  uint32_t u = c.u;
  u += 0x7FFFu + ((u >> 16) & 1u);   // RNE
  return (unsigned short)(u >> 16);
}

// async global->LDS, 16B/lane; LDS dest is wave-uniform base + lane*16.
__device__ __forceinline__ void gl16(const void* g, void* l) {
  __builtin_amdgcn_global_load_lds(
      (const __attribute__((address_space(1))) unsigned int*)g,
      (__attribute__((address_space(3))) unsigned int*)l, 16, 0, 0);
}

// ----------------- k_qkv: 128x128, 256 thr, fused vT, XCD map (round 4) ----
__global__ __launch_bounds__(256) void k_qkv(
    const short* __restrict__ A, const short* __restrict__ B,
    short* __restrict__ Cb, short* __restrict__ vT,
    const float* __restrict__ b0, const float* __restrict__ b1,
    const float* __restrict__ b2)
{
  // 1536 blocks: xcd(b&7) owns tileM rows xcd*8.. for ALL z (A-slab shared)
  const int b = blockIdx.x;
  const int xcd = b & 7, r = b >> 3;
  const int z = r >> 6;
  const int mem = r & 63;
  const int tm = xcd * 8 + (mem >> 3);
  const int tn = mem & 7;

  __shared__ short lds[18432];   // 2 bufs x (sA 4096 | sB 4096); overlay 4x4608

  const int tid  = threadIdx.x;
  const int lane = tid & 63;
  const int wid  = tid >> 6;
  const long tileM = (long)tm * 128;
  const long tileN = (long)tn * 128;
  const short* Az = A;
  const short* Bz = B + (long)z * 1048576L;

  const int c0 = tid, c1 = 256 + tid;
  const short* gA0 = Az + (tileM + (c0 >> 2)) * 1024 + (c0 & 3) * 8;
  const short* gA1 = Az + (tileM + (c1 >> 2)) * 1024 + (c1 & 3) * 8;
  const short* gB0 = Bz + (tileN + (c0 >> 2)) * 1024 + (c0 & 3) * 8;
  const short* gB1 = Bz + (tileN + (c1 >> 2)) * 1024 + (c1 & 3) * 8;

  const int fr = lane & 15, quad = lane >> 4;
  const int waveM = (wid >> 1) * 64, waveN = (wid & 1) * 64;

  f32x4 acc[4][4] = {};

  {
    short* base = lds;
    gl16(gA0, base + c0 * 8);
    gl16(gA1, base + c1 * 8);
    gl16(gB0, base + 4096 + c0 * 8);
    gl16(gB1, base + 4096 + c1 * 8);
  }

  for (int t = 0; t < 32; ++t) {
    __syncthreads();
    if (t + 1 < 32) {
      const int kt = (t + 1) << 5;
      short* base = lds + ((t + 1) & 1) * 8192;
      gl16(gA0 + kt, base + c0 * 8);
      gl16(gA1 + kt, base + c1 * 8);
      gl16(gB0 + kt, base + 4096 + c0 * 8);
      gl16(gB1 + kt, base + 4096 + c1 * 8);
    }
    const short* sA = lds + (t & 1) * 8192;
    const short* sB = sA + 4096;
    short8 af[4], bf[4];
#pragma unroll
    for (int i = 0; i < 4; ++i)
      af[i] = *(const short8*)&sA[(waveM + i * 16 + fr) * 32 + quad * 8];
#pragma unroll
    for (int j = 0; j < 4; ++j)
      bf[j] = *(const short8*)&sB[(waveN + j * 16 + fr) * 32 + quad * 8];
#pragma unroll
    for (int i = 0; i < 4; ++i)
#pragma unroll
      for (int j = 0; j < 4; ++j)
        acc[i][j] = __builtin_amdgcn_mfma_f32_16x16x32_bf16(af[i], bf[j],
                                                            acc[i][j], 0, 0, 0);
  }

  // C/D layout: row=(lane>>4)*4+r, col=lane&15 (m89/m91-verified).
  if (z == 2) {
    // v-tile: add bias, write TRANSPOSED scratch [d][t], store vT[b][d][t]
    __syncthreads();
    short* scr = lds + wid * 4608;   // [64][72]
#pragma unroll
    for (int j = 0; j < 4; ++j) {
      const float bv = b2[tileN + waveN + j * 16 + fr];
#pragma unroll
      for (int i = 0; i < 4; ++i)
#pragma unroll
        for (int r = 0; r < 4; ++r)
          scr[(j * 16 + fr) * 72 + i * 16 + quad * 4 + r] =
              (short)f2bf(acc[i][j][r] + bv);
    }
    const int gb = tm >> 4;
    const long t0 = (long)(tm & 15) * 128 + waveM;
#pragma unroll
    for (int c = 0; c < 8; ++c) {
      const int rr = c * 8 + (lane >> 3);
      const int cc = (lane & 7) * 8;
      short8 v = *(const short8*)&scr[rr * 72 + cc];
      const long gd = tileN + waveN + rr;
      *(short8*)(vT + ((long)gb << 21) + gd * 2048 + t0 + cc) = v;
    }
  } else {
    __syncthreads();
    short* scr = lds + wid * 4608;   // [64][72]
    short* C = Cb + (long)z * 8388608L;
    const float* bias = (z == 0) ? b0 : b1;
#pragma unroll
    for (int j = 0; j < 4; ++j) {
      const float bv = bias[tileN + waveN + j * 16 + fr];
#pragma unroll
      for (int i = 0; i < 4; ++i)
#pragma unroll
        for (int r = 0; r < 4; ++r)
          scr[(i * 16 + quad * 4 + r) * 72 + j * 16 + fr] =
              (short)f2bf(acc[i][j][r] + bv);
    }
#pragma unroll
    for (int c = 0; c < 8; ++c) {
      const int row = c * 8 + (lane >> 3);
      const int col = (lane & 7) * 8;
      short8 v = *(const short8*)&scr[row * 72 + col];
      *(short8*)(C + (tileM + waveM + row) * 1024 + tileN + waveN + col) = v;
    }
  }
}

// ---------------- k_score: 256x256 tile, 1024 threads (16 waves) -----------
// P' = exp2(q@k^T * scale) bf16 + rowsum atomics. K=1024, BK=32 dbuf.
// Grid 256 blocks (1/CU): z=b>>6, tm=(b&63)>>3, tn=b&7.
__global__ __launch_bounds__(1024) void k_score(
    const short* __restrict__ A, const short* __restrict__ B,
    short* __restrict__ Pp, float scale, float* __restrict__ rowsum)
{
  const int b = blockIdx.x;
  const int z = b >> 6;
  const int tm = (b & 63) >> 3, tn = b & 7;

  // staging: buf t at lds + (t&1)*16384 (sA 256x32 = 8192 | sB 8192 shorts).
  // epilogue scratch overlays: 4 waves/round x [64][72] shorts.
  __shared__ short lds[32768];

  const int tid  = threadIdx.x;
  const int lane = tid & 63;
  const int wid  = tid >> 6;          // 0..15
  const long tileM = (long)tm * 256;
  const long tileN = (long)tn * 256;
  const short* Az = A + (long)z * 2097152L;
  const short* Bz = B + (long)z * 2097152L;

  // per k-tile: A 1024 chunks + B 1024 chunks of 16B; 1 A + 1 B per thread.
  const short* gA = Az + (tileM + (tid >> 2)) * 1024 + (tid & 3) * 8;
  const short* gB = Bz + (tileN + (tid >> 2)) * 1024 + (tid & 3) * 8;

  const int fr = lane & 15, quad = lane >> 4;
  const int waveM = (wid >> 2) * 64, waveN = (wid & 3) * 64;

  f32x4 acc[4][4] = {};

  {
    short* base = lds;
    gl16(gA, base + tid * 8);
    gl16(gB, base + 8192 + tid * 8);
  }

  for (int t = 0; t < 32; ++t) {
    __syncthreads();
    if (t + 1 < 32) {
      const int kt = (t + 1) << 5;
      short* base = lds + ((t + 1) & 1) * 16384;
      gl16(gA + kt, base + tid * 8);
      gl16(gB + kt, base + 8192 + tid * 8);
    }
    const short* sA = lds + (t & 1) * 16384;
    const short* sB = sA + 8192;
    short8 af[4], bf[4];
#pragma unroll
    for (int i = 0; i < 4; ++i)
      af[i] = *(const short8*)&sA[(waveM + i * 16 + fr) * 32 + quad * 8];
#pragma unroll
    for (int j = 0; j < 4; ++j)
      bf[j] = *(const short8*)&sB[(waveN + j * 16 + fr) * 32 + quad * 8];
#pragma unroll
    for (int i = 0; i < 4; ++i)
#pragma unroll
      for (int j = 0; j < 4; ++j)
        acc[i][j] = __builtin_amdgcn_mfma_f32_16x16x32_bf16(af[i], bf[j],
                                                            acc[i][j], 0, 0, 0);
  }

  // exp2 + rowsum partials (C/D layout: row=(lane>>4)*4+r, col=lane&15)
#pragma unroll
  for (int i = 0; i < 4; ++i)
#pragma unroll
    for (int j = 0; j < 4; ++j)
#pragma unroll
      for (int r = 0; r < 4; ++r)
        acc[i][j][r] = exp2f(acc[i][j][r] * scale);
#pragma unroll
  for (int i = 0; i < 4; ++i)
#pragma unroll
    for (int r = 0; r < 4; ++r) {
      float s = acc[i][0][r] + acc[i][1][r] + acc[i][2][r] + acc[i][3][r];
      s += __shfl_xor(s, 1);
      s += __shfl_xor(s, 2);
      s += __shfl_xor(s, 4);
      s += __shfl_xor(s, 8);
      if (fr == 0)
        atomicAdd(&rowsum[(long)z * 2048 + tileM + waveM + i * 16 + quad * 4 + r], s);
    }

  // bf16 out via LDS transpose, 4 rounds of 4 waves (scratch 4x4608 shorts)
  short* C = Pp + (long)z * 4194304L;
  const int wgrp = wid >> 2, wloc = wid & 3;
  for (int rnd = 0; rnd < 4; ++rnd) {
    __syncthreads();   // staging reads / previous round's reads done
    if (wgrp == rnd) {
      short* scr = lds + wloc * 4608;   // [64][72]
#pragma unroll
      for (int j = 0; j < 4; ++j)
#pragma unroll
        for (int i = 0; i < 4; ++i)
#pragma unroll
          for (int r = 0; r < 4; ++r)
            scr[(i * 16 + quad * 4 + r) * 72 + j * 16 + fr] =
                (short)f2bf(acc[i][j][r]);
      // same-wave ds_write->ds_read ordered via lgkmcnt
#pragma unroll
      for (int c = 0; c < 8; ++c) {
        const int row = c * 8 + (lane >> 3);
        const int col = (lane & 7) * 8;
        short8 v = *(const short8*)&scr[row * 72 + col];
        *(short8*)(C + (tileM + waveM + row) * 2048 + tileN + waveN + col) = v;
      }
    }
  }
}

// ----------------- k_pv: 128x128, 256 thr, swizzled (round 4) --------------
// out = (P' @ vT^T) / rowsum, fp32. K=2048, BK=32 dbuf. Grid 512.
__global__ __launch_bounds__(256) void k_pv(
    const short* __restrict__ A, const short* __restrict__ B,
    float* __restrict__ Cf, float* __restrict__ rowsum)
{
  const int b = blockIdx.x;
  const int s = b & 7, r0_ = b >> 3;
  const int z = r0_ >> 4;
  const int mem = r0_ & 15;
  const int tm = (s >> 1) * 4 + (mem >> 2);
  const int tn = (s & 1) * 4 + (mem & 3);

  __shared__ short lds[18432];

  const int tid  = threadIdx.x;
  const int lane = tid & 63;
  const int wid  = tid >> 6;
  const long tileM = (long)tm * 128;
  const long tileN = (long)tn * 128;
  const short* Az = A + (long)z * 4194304L;
  const short* Bz = B + (long)z * 2097152L;

  const int c0 = tid, c1 = 256 + tid;
  const short* gA0 = Az + (tileM + (c0 >> 2)) * 2048 + (c0 & 3) * 8;
  const short* gA1 = Az + (tileM + (c1 >> 2)) * 2048 + (c1 & 3) * 8;
  const short* gB0 = Bz + (tileN + (c0 >> 2)) * 2048 + (c0 & 3) * 8;
  const short* gB1 = Bz + (tileN + (c1 >> 2)) * 2048 + (c1 & 3) * 8;

  const int fr = lane & 15, quad = lane >> 4;
  const int waveM = (wid >> 1) * 64, waveN = (wid & 1) * 64;

  f32x4 acc[4][4] = {};

  {
    short* base = lds;
    gl16(gA0, base + c0 * 8);
    gl16(gA1, base + c1 * 8);
    gl16(gB0, base + 4096 + c0 * 8);
    gl16(gB1, base + 4096 + c1 * 8);
  }

  for (int t = 0; t < 64; ++t) {
    __syncthreads();
    if (t + 1 < 64) {
      const int kt = (t + 1) << 5;
      short* base = lds + ((t + 1) & 1) * 8192;
      gl16(gA0 + kt, base + c0 * 8);
      gl16(gA1 + kt, base + c1 * 8);
      gl16(gB0 + kt, base + 4096 + c0 * 8);
      gl16(gB1 + kt, base + 4096 + c1 * 8);
    }
    const short* sA = lds + (t & 1) * 8192;
    const short* sB = sA + 4096;
    short8 af[4], bf[4];
#pragma unroll
    for (int i = 0; i < 4; ++i)
      af[i] = *(const short8*)&sA[(waveM + i * 16 + fr) * 32 + quad * 8];
#pragma unroll
    for (int j = 0; j < 4; ++j)
      bf[j] = *(const short8*)&sB[(waveN + j * 16 + fr) * 32 + quad * 8];
#pragma unroll
    for (int i = 0; i < 4; ++i)
#pragma unroll
      for (int j = 0; j < 4; ++j)
        acc[i][j] = __builtin_amdgcn_mfma_f32_16x16x32_bf16(af[i], bf[j],
                                                            acc[i][j], 0, 0, 0);
  }

  float* C = Cf + (long)z * 2097152L;
#pragma unroll
  for (int i = 0; i < 4; ++i)
#pragma unroll
    for (int r = 0; r < 4; ++r) {
      const long gr = tileM + waveM + i * 16 + quad * 4 + r;
      const float rinv = 1.0f / rowsum[(long)z * 2048 + gr];
#pragma unroll
      for (int j = 0; j < 4; ++j)
        C[gr * 1024 + tileN + waveN + j * 16 + fr] = acc[i][j][r] * rinv;
    }
}

// prep: blocks [0,8192) cvt x -> bf16; [8192,11264) W^T -> bf16; 11264 zero rs
__global__ __launch_bounds__(256) void k_prep(
    const float4* __restrict__ x, ushort4* __restrict__ xb,
    const float* __restrict__ Wq, const float* __restrict__ Wk,
    const float* __restrict__ Wv, short* __restrict__ WT,
    float* __restrict__ rs)
{
  __shared__ short tile[32][33];
  const int b = blockIdx.x;
  if (b < 8192) {
    const long i = (long)b * 256 + threadIdx.x;
    float4 v = x[i];
    ushort4 o;
    o.x = f2bf(v.x); o.y = f2bf(v.y); o.z = f2bf(v.z); o.w = f2bf(v.w);
    xb[i] = o;
  } else if (b < 11264) {
    const int idx = b - 8192;
    const int z = idx >> 10, rem = idx & 1023;
    const float* W = (z == 0) ? Wq : ((z == 1) ? Wk : Wv);
    short* d = WT + (long)z * 1024 * 1024;
    const int n0 = (rem & 31) * 32, d0 = (rem >> 5) * 32;
    const int tx = threadIdx.x & 31, ty = threadIdx.x >> 5;
#pragma unroll
    for (int p = 0; p < 4; ++p)
      tile[ty + p * 8][tx] = (short)f2bf(W[(long)(d0 + ty + p * 8) * 1024 + n0 + tx]);
    __syncthreads();
#pragma unroll
    for (int p = 0; p < 4; ++p)
      d[(long)(n0 + ty + p * 8) * 1024 + d0 + tx] = tile[tx][ty + p * 8];
  } else {
#pragma unroll
    for (int p = 0; p < 32; ++p)
      rs[p * 256 + threadIdx.x] = 0.0f;
  }
}

extern "C" void kernel_launch(void* const* d_in, const int* in_sizes, int n_in,
                              void* d_out, int out_size, void* d_ws, size_t ws_size,
                              hipStream_t stream) {
  const float* x  = (const float*)d_in[0];
  const float* Wq = (const float*)d_in[1];
  const float* bq = (const float*)d_in[2];
  const float* Wk = (const float*)d_in[3];
  const float* bk = (const float*)d_in[4];
  const float* Wv = (const float*)d_in[5];
  const float* bv = (const float*)d_in[6];

  char* ws = (char*)d_ws;
  short* xb  = (short*)(ws);                  // 16 MB
  short* wt  = (short*)(ws + 16777216);       // 6 MB
  short* qkv = (short*)(ws + 23068672);       // 48 MB: q | k | vT
  short* Pp  = (short*)(ws + 73400320);       // 32 MB: [4][2048][2048] bf16
  float* rs  = (float*)(ws + 106954752);      // 32 KB: [4][2048] fp32
  short* vT  = qkv + 2L * 8388608;            // [4][1024][2048] bf16

  // 1. prep: xb, wt, rowsum=0
  k_prep<<<11265, 256, 0, stream>>>((const float4*)x, (ushort4*)xb,
                                    Wq, Wk, Wv, wt, rs);
  // 2. q,k = x@W+b (bf16); v written transposed into vT
  k_qkv<<<1536, 256, 0, stream>>>(xb, wt, qkv, vT, bq, bk, bv);
  // 3. P' = exp2(q@k^T * scale*log2e), bf16 + rowsum atomics  [256^2 tiles]
  k_score<<<256, 1024, 0, stream>>>(qkv, qkv + 8388608, Pp,
                                    0.03125f * 1.44269504088896f, rs);
  // 4. out = (P' @ vT^T) / rowsum  (fp32 -> d_out)
  k_pv<<<512, 256, 0, stream>>>(Pp, vT, (float*)d_out, rs);
}